// Round 8
// baseline (219.738 us; speedup 1.0000x reference)
//
#include <hip/hip_runtime.h>
#include <stdint.h>

// Problem constants (match reference)
#define B_ 4096
#define C_ 200
#define P_ 32
#define F_ 512
#define N_ (C_*P_)        // 6400 prototypes total
#define ALPHA_ 5.0
#define EPS_ 1e-8

typedef unsigned char u8;
typedef __attribute__((ext_vector_type(4))) float floatx4;  // MFMA C/D frag

union frag16 { int4 v; long l[2]; };   // 16 fp8 = two MFMA k-slices (virtual-K)

// Completion-counter block, placed past the 8,692,736-byte data layout (arena is 256 MiB
// per the fill's WRITE_SIZE). done[8]: per-m-panel score-block countdown; pdone: panel-
// select countdown; pair[8][2]: per-panel f64 partial sums (target, wrong).
struct Cnt { int done[8]; int pdone; int pad[3]; double pair[8][2]; };

// ---------- prep: fp32 -> fp8 e4m3 packed + row sum-of-squares (x2 | p2) ----------
// Proven R5 version + counter zeroing (dispatch-1 -> visible to score by stream order).
__global__ __launch_bounds__(512)
void prep_kernel(const float* __restrict__ outputs, const float* __restrict__ clusters,
                 u8* __restrict__ At, u8* __restrict__ Bt, float* __restrict__ sumsq,
                 int* __restrict__ cnt_ints) {
    const int tid = threadIdx.x;
    const int blk = blockIdx.x;
    if (blk == 0 && tid < 9) cnt_ints[tid] = 0;    // done[8] + pdone
    const float* src; u8* dst; int tm, rbase;
    if (blk < B_ / 16) { tm = blk;            src = outputs;  dst = At; rbase = 0;  }
    else               { tm = blk - B_ / 16;  src = clusters; dst = Bt; rbase = B_; }
    const int o  = tm * 512 + tid;           // packed 16B-unit index
    const int kc = tid >> 6, q = (tid >> 4) & 3, r = tid & 15;
    const int row = tm * 16 + r;

    const float4* s = (const float4*)(src + (size_t)row * F_ + kc * 64 + q * 16);
    float4 v0 = s[0], v1 = s[1], v2 = s[2], v3 = s[3];
    int4 w;
    w.x = __builtin_amdgcn_cvt_pk_fp8_f32(v0.x, v0.y, 0, false);
    w.x = __builtin_amdgcn_cvt_pk_fp8_f32(v0.z, v0.w, w.x, true);
    w.y = __builtin_amdgcn_cvt_pk_fp8_f32(v1.x, v1.y, 0, false);
    w.y = __builtin_amdgcn_cvt_pk_fp8_f32(v1.z, v1.w, w.y, true);
    w.z = __builtin_amdgcn_cvt_pk_fp8_f32(v2.x, v2.y, 0, false);
    w.z = __builtin_amdgcn_cvt_pk_fp8_f32(v2.z, v2.w, w.z, true);
    w.w = __builtin_amdgcn_cvt_pk_fp8_f32(v3.x, v3.y, 0, false);
    w.w = __builtin_amdgcn_cvt_pk_fp8_f32(v3.z, v3.w, w.w, true);
    *(int4*)(dst + (size_t)o * 16) = w;

    float ss = v0.x*v0.x + v0.y*v0.y + v0.z*v0.z + v0.w*v0.w
             + v1.x*v1.x + v1.y*v1.y + v1.z*v1.z + v1.w*v1.w
             + v2.x*v2.x + v2.y*v2.y + v2.z*v2.z + v2.w*v2.w
             + v3.x*v3.x + v3.y*v3.y + v3.z*v3.z + v3.w*v3.w;
    ss += __shfl_xor(ss, 16);                // fold q^1
    ss += __shfl_xor(ss, 32);                // fold q^2 -> per-row partial (this kc)
    __shared__ float red[8][16];
    if ((tid & 63) < 16) red[kc][r] = ss;
    __syncthreads();
    if (tid < 16) {
        float t = 0.f;
#pragma unroll
        for (int k = 0; k < 8; ++k) t += red[k][tid];
        sumsq[rbase + tm * 16 + tid] = t;
    }
}

// ---------- score+select+finalize: ONE kernel via last-block-done pattern ----------
// K-loop identical to R7 (barrier-free: A direct from global, 32KB B-tile staged once).
// After each block's min_d panel-stores: threadfence + done[by] countdown; the 100th
// (last) block of a panel runs select for its 512 samples in-place (coalesced [C][B]
// reads, L2-warm), f64-reduces, and the 8th panel-finisher computes the loss.
// All reductions in fixed index order -> deterministic.
#define BMs 512
#define BNs 64

typedef const __attribute__((address_space(1))) unsigned int gu32_t;
typedef __attribute__((address_space(3))) unsigned int lu32_t;

__device__ __forceinline__ void gld16(const u8* g, u8* l) {
    __builtin_amdgcn_global_load_lds((gu32_t*)g, (lu32_t*)l, 16, 0, 0);
}

__global__ __launch_bounds__(512, 4)
void score_kernel(const u8* __restrict__ At, const u8* __restrict__ Bt,
                  const float* __restrict__ sumsq, const int* __restrict__ tgt,
                  float* __restrict__ min_d, Cnt* __restrict__ cnt,
                  float* __restrict__ out) {
    __shared__ __align__(16) u8 ldsB[32768];   // B-tile: 4 col-subtiles x 8 kc x 1KB

    const int tid  = threadIdx.x;
    const int lane = tid & 63;
    const int w    = tid >> 6;            // wave 0..7, owns rows [w*64, +64) of the m-panel
    const int mrow = lane & 15;
    const int quad = lane >> 4;
    const int l16  = lane * 16;

    const int bid = blockIdx.x;           // 800 blocks
    const int by  = bid & 7;              // m-panel 0..7 (= XCD under round-robin dispatch)
    const int bx  = bid >> 3;             // n-tile 0..99

    const float* p2 = sumsq + B_;

    // stage the whole 32KB B-tile (contiguous in Bt) once; lane-linear dest
#pragma unroll
    for (int i = 0; i < 4; ++i)
        gld16(Bt + (size_t)bx * 32768 + i * 8192 + tid * 16, ldsB + i * 8192 + tid * 16);
    asm volatile("s_waitcnt vmcnt(0)" ::: "memory");
    __syncthreads();

    floatx4 zf = {0.f, 0.f, 0.f, 0.f};
    floatx4 acc[4][4];
#pragma unroll
    for (int i = 0; i < 4; ++i)
#pragma unroll
        for (int j = 0; j < 4; ++j) acc[i][j] = zf;

    // A row-subtile base: rows (by*512 + w*64 + t*16 .. +16) -> subtile index by*32+w*4+t
    const u8* ap = At + (((size_t)(by * 32 + w * 4)) << 13);   // 4 subtiles x 8KB

#pragma unroll
    for (int kc = 0; kc < 8; ++kc) {
        frag16 a[4], b[4];
#pragma unroll
        for (int t = 0; t < 4; ++t)
            a[t].v = *(const int4*)(ap + ((t * 8 + kc) << 10) + l16);
#pragma unroll
        for (int t = 0; t < 4; ++t)
            b[t].v = *(const int4*)(ldsB + ((t * 8 + kc) << 10) + l16);
#pragma unroll
        for (int s = 0; s < 2; ++s)
#pragma unroll
            for (int mt = 0; mt < 4; ++mt)
#pragma unroll
                for (int nt = 0; nt < 4; ++nt)
                    acc[mt][nt] = __builtin_amdgcn_mfma_f32_16x16x32_fp8_fp8(
                        a[mt].l[s], b[nt].l[s], acc[mt][nt], 0, 0, 0);
    }

    // Epilogue: score = p2[n] - 2*xp; per-class min over 32 protos (2 classes per tile).
    // C/D: col = lane&15 (proto), row = quad*4 + reg (sample). Transposed store
    // min_d[cls*B + row]: one float4 per quad-lane, 4 quads = contiguous 64B.
    float pg[4];
#pragma unroll
    for (int nt = 0; nt < 4; ++nt) pg[nt] = p2[bx * BNs + nt * 16 + mrow];

#pragma unroll
    for (int ch = 0; ch < 2; ++ch) {
        const int cls = bx * 2 + ch;
#pragma unroll
        for (int mt = 0; mt < 4; ++mt) {
            float4 vv;
#pragma unroll
            for (int reg = 0; reg < 4; ++reg) {
                float v = fminf(pg[ch * 2]     - 2.0f * acc[mt][ch * 2][reg],
                                pg[ch * 2 + 1] - 2.0f * acc[mt][ch * 2 + 1][reg]);
#pragma unroll
                for (int m = 8; m >= 1; m >>= 1) v = fminf(v, __shfl_xor(v, m));
                ((float*)&vv)[reg] = v;
            }
            if (mrow == 0) {
                int grow = by * BMs + w * 64 + mt * 16 + quad * 4;
                *(float4*)&min_d[(size_t)cls * B_ + grow] = vv;
            }
        }
    }

    // ---- panel completion: last of the 100 blocks of panel `by` runs select ----
    __threadfence();                       // make this block's min_d stores device-visible
    __syncthreads();                       // all threads' fences done before the count
    __shared__ int slast;
    if (tid == 0) slast = (atomicAdd(&cnt->done[by], 1) == 99);
    __syncthreads();
    if (!slast) return;
    __threadfence();                       // acquire: see all 100 blocks' panel stores

    // select: thread = sample b (coalesced across the 512-wide panel), 200 class loads
    const int b  = by * BMs + tid;
    const int tc = tgt[b];
    float bw = 3.4e38f, vt = 0.f;
#pragma unroll 8
    for (int c = 0; c < C_; ++c) {
        float v = min_d[(size_t)c * B_ + b];
        if (c == tc) vt = v;
        else         bw = fminf(bw, v);
    }
    const float xx = sumsq[b];             // x2
    double tval = (double)(xx + vt);       // = ||x - p_target*||^2 (fp8-dot approx)
    double wval = (double)(xx + bw);       // = ||x - p_wrong*||^2
#pragma unroll
    for (int m = 32; m >= 1; m >>= 1) {
        tval += __shfl_xor(tval, m);
        wval += __shfl_xor(wval, m);
    }
    __shared__ double rs[8][2];
    if ((tid & 63) == 0) { rs[w][0] = tval; rs[w][1] = wval; }
    __syncthreads();
    if (tid == 0) {
        double s1 = 0.0, s2 = 0.0;
#pragma unroll
        for (int k = 0; k < 8; ++k) { s1 += rs[k][0]; s2 += rs[k][1]; }
        cnt->pair[by][0] = s1;
        cnt->pair[by][1] = s2;
        __threadfence();
        if (atomicAdd(&cnt->pdone, 1) == 7) {      // 8th panel-finisher -> loss
            __threadfence();
            double t1 = 0.0, t2 = 0.0;
#pragma unroll
            for (int k = 0; k < 8; ++k) { t1 += cnt->pair[k][0]; t2 += cnt->pair[k][1]; }
            const double denom = (double)B_ * (double)F_;
            out[0] = (float)((1.0 - ALPHA_) * (t1 / denom) + ALPHA_ / ((t2 / denom) + EPS_));
        }
    }
}

// ---------- launch: TWO dispatches ----------
extern "C" void kernel_launch(void* const* d_in, const int* in_sizes, int n_in,
                              void* d_out, int out_size, void* d_ws, size_t ws_size,
                              hipStream_t stream) {
    const float* outputs  = (const float*)d_in[0];
    const float* clusters = (const float*)d_in[1];
    const int*   tgt      = (const int*)d_in[2];
    float* out = (float*)d_out;

    char* ws = (char*)d_ws;
    // workspace layout (16B-aligned)
    u8*     At      = (u8*)(ws);                     // packed A: 2,097,152
    u8*     Bt      = (u8*)(ws + 2097152);           // packed B: 3,276,800
    float*  sumsq   = (float*)(ws + 5373952);        // 10496*4 (x2 | p2)
    float*  min_d   = (float*)(ws + 5415936);        // [C][B] 200*4096*4, ends 8,692,736
    Cnt*    cnt     = (Cnt*)(ws + 8692736);          // counters + f64 panel partials

    prep_kernel<<<B_ / 16 + N_ / 16, 512, 0, stream>>>(outputs, clusters, At, Bt, sumsq,
                                                       (int*)cnt);                        // 656
    score_kernel<<<(B_ / BMs) * (N_ / BNs), 512, 0, stream>>>(At, Bt, sumsq, tgt,
                                                              min_d, cnt, out);          // 800
}

// Round 9
// 99.789 us; speedup vs baseline: 2.2020x; 2.2020x over previous
//
#include <hip/hip_runtime.h>
#include <stdint.h>

// Problem constants (match reference)
#define B_ 4096
#define C_ 200
#define P_ 32
#define F_ 512
#define N_ (C_*P_)        // 6400 prototypes total
#define ALPHA_ 5.0
#define EPS_ 1e-8

typedef unsigned char u8;
typedef __attribute__((ext_vector_type(4))) float floatx4;  // MFMA C/D frag

union frag16 { int4 v; long l[2]; };   // 16 fp8 = two MFMA k-slices (virtual-K)

// ---------- prep: fp32 -> fp8 e4m3 packed + row sum-of-squares (x2 | p2) ----------
// Proven R5 version: block = 512 threads = 8 waves = kc 0..7 of ONE 16-row group.
__global__ __launch_bounds__(512)
void prep_kernel(const float* __restrict__ outputs, const float* __restrict__ clusters,
                 u8* __restrict__ At, u8* __restrict__ Bt, float* __restrict__ sumsq) {
    const int tid = threadIdx.x;
    const int blk = blockIdx.x;
    const float* src; u8* dst; int tm, rbase;
    if (blk < B_ / 16) { tm = blk;            src = outputs;  dst = At; rbase = 0;  }
    else               { tm = blk - B_ / 16;  src = clusters; dst = Bt; rbase = B_; }
    const int o  = tm * 512 + tid;           // packed 16B-unit index
    const int kc = tid >> 6, q = (tid >> 4) & 3, r = tid & 15;
    const int row = tm * 16 + r;

    const float4* s = (const float4*)(src + (size_t)row * F_ + kc * 64 + q * 16);
    float4 v0 = s[0], v1 = s[1], v2 = s[2], v3 = s[3];
    int4 w;
    w.x = __builtin_amdgcn_cvt_pk_fp8_f32(v0.x, v0.y, 0, false);
    w.x = __builtin_amdgcn_cvt_pk_fp8_f32(v0.z, v0.w, w.x, true);
    w.y = __builtin_amdgcn_cvt_pk_fp8_f32(v1.x, v1.y, 0, false);
    w.y = __builtin_amdgcn_cvt_pk_fp8_f32(v1.z, v1.w, w.y, true);
    w.z = __builtin_amdgcn_cvt_pk_fp8_f32(v2.x, v2.y, 0, false);
    w.z = __builtin_amdgcn_cvt_pk_fp8_f32(v2.z, v2.w, w.z, true);
    w.w = __builtin_amdgcn_cvt_pk_fp8_f32(v3.x, v3.y, 0, false);
    w.w = __builtin_amdgcn_cvt_pk_fp8_f32(v3.z, v3.w, w.w, true);
    *(int4*)(dst + (size_t)o * 16) = w;

    float ss = v0.x*v0.x + v0.y*v0.y + v0.z*v0.z + v0.w*v0.w
             + v1.x*v1.x + v1.y*v1.y + v1.z*v1.z + v1.w*v1.w
             + v2.x*v2.x + v2.y*v2.y + v2.z*v2.z + v2.w*v2.w
             + v3.x*v3.x + v3.y*v3.y + v3.z*v3.z + v3.w*v3.w;
    ss += __shfl_xor(ss, 16);                // fold q^1
    ss += __shfl_xor(ss, 32);                // fold q^2 -> per-row partial (this kc)
    __shared__ float red[8][16];
    if ((tid & 63) < 16) red[kc][r] = ss;
    __syncthreads();
    if (tid < 16) {
        float t = 0.f;
#pragma unroll
        for (int k = 0; k < 8; ++k) t += red[k][tid];
        sumsq[rbase + tm * 16 + tid] = t;
    }
}

// ---------- score: barrier-free K-loop + register A-prefetch + fine-grain grid ----------
// R8 direct counters: VGPR_Count=64 -> compiler allocated NO prefetch regs, so each kc
// serialized {issue 4 A-loads -> wait -> 32 MFMA}. Fix 1: manual 1-deep A-fragment
// double-buffer (aX/aY, unroll x2, static indices) so kc+1 loads fly under kc's MFMA
// cluster. Fix 2: 800 8-wave blocks (3.125/CU, 28% tail stretch) -> 1600 4-wave blocks.
// Fix 3: T5 setprio around the MFMA cluster (barrier-free waves = role diversity).
#define BMs 256
#define BNs 64

typedef const __attribute__((address_space(1))) unsigned int gu32_t;
typedef __attribute__((address_space(3))) unsigned int lu32_t;

__device__ __forceinline__ void gld16(const u8* g, u8* l) {
    __builtin_amdgcn_global_load_lds((gu32_t*)g, (lu32_t*)l, 16, 0, 0);
}

__global__ __launch_bounds__(256)
void score_kernel(const u8* __restrict__ At, const u8* __restrict__ Bt,
                  const float* __restrict__ p2, float* __restrict__ min_d) {
    __shared__ __align__(16) u8 ldsB[32768];   // B-tile: 4 col-subtiles x 8 kc x 1KB

    const int tid  = threadIdx.x;
    const int lane = tid & 63;
    const int w    = tid >> 6;            // wave 0..3, owns rows [w*64, +64) of the m-tile
    const int mrow = lane & 15;
    const int quad = lane >> 4;
    const int l16  = lane * 16;

    const int bid = blockIdx.x;           // 1600 blocks
    const int by  = bid & 15;             // m-tile 0..15 (round-robin: 2 A-panels per XCD)
    const int bx  = bid >> 4;             // n-tile 0..99

    // stage the whole 32KB B-tile (contiguous in Bt) once; lane-linear dest
#pragma unroll
    for (int i = 0; i < 8; ++i)
        gld16(Bt + (size_t)bx * 32768 + i * 4096 + tid * 16, ldsB + i * 4096 + tid * 16);
    asm volatile("s_waitcnt vmcnt(0)" ::: "memory");
    __syncthreads();

    floatx4 zf = {0.f, 0.f, 0.f, 0.f};
    floatx4 acc[4][4];
#pragma unroll
    for (int i = 0; i < 4; ++i)
#pragma unroll
        for (int j = 0; j < 4; ++j) acc[i][j] = zf;

    // A row-subtile base: rows by*256 + w*64 + t*16 -> 16-row-group index by*16 + w*4 + t
    const u8* ap = At + (((size_t)(by * 16 + w * 4)) << 13);   // 4 subtiles x 8KB

    frag16 aX[4], aY[4], b[4];
#pragma unroll
    for (int t = 0; t < 4; ++t)                        // preload kc=0
        aX[t].v = *(const int4*)(ap + ((t * 8 + 0) << 10) + l16);

#define MFMA_CLUSTER(AF)                                                        \
    do {                                                                        \
        __builtin_amdgcn_s_setprio(1);                                          \
        _Pragma("unroll")                                                       \
        for (int s = 0; s < 2; ++s)                                             \
            _Pragma("unroll")                                                   \
            for (int mt = 0; mt < 4; ++mt)                                      \
                _Pragma("unroll")                                               \
                for (int nt = 0; nt < 4; ++nt)                                  \
                    acc[mt][nt] = __builtin_amdgcn_mfma_f32_16x16x32_fp8_fp8(   \
                        AF[mt].l[s], b[nt].l[s], acc[mt][nt], 0, 0, 0);         \
        __builtin_amdgcn_s_setprio(0);                                          \
    } while (0)

#pragma unroll
    for (int kc = 0; kc < 8; kc += 2) {
        // even half: prefetch kc+1 into aY, compute on aX
        if (kc + 1 < 8)
#pragma unroll
            for (int t = 0; t < 4; ++t)
                aY[t].v = *(const int4*)(ap + ((t * 8 + kc + 1) << 10) + l16);
#pragma unroll
        for (int t = 0; t < 4; ++t)
            b[t].v = *(const int4*)(ldsB + ((t * 8 + kc) << 10) + l16);
        MFMA_CLUSTER(aX);
        // odd half: prefetch kc+2 into aX, compute on aY
        if (kc + 2 < 8)
#pragma unroll
            for (int t = 0; t < 4; ++t)
                aX[t].v = *(const int4*)(ap + ((t * 8 + kc + 2) << 10) + l16);
#pragma unroll
        for (int t = 0; t < 4; ++t)
            b[t].v = *(const int4*)(ldsB + ((t * 8 + kc + 1) << 10) + l16);
        MFMA_CLUSTER(aY);
    }
#undef MFMA_CLUSTER

    // Epilogue: score = p2[n] - 2*xp; per-class min over 32 protos (2 classes per tile).
    // C/D: col = lane&15 (proto), row = quad*4 + reg (sample). Transposed store
    // min_d[cls*B + row]: one float4 per quad-lane, 4 quads = contiguous 64B.
    float pg[4];
#pragma unroll
    for (int nt = 0; nt < 4; ++nt) pg[nt] = p2[bx * BNs + nt * 16 + mrow];

#pragma unroll
    for (int ch = 0; ch < 2; ++ch) {
        const int cls = bx * 2 + ch;
#pragma unroll
        for (int mt = 0; mt < 4; ++mt) {
            float4 vv;
#pragma unroll
            for (int reg = 0; reg < 4; ++reg) {
                float v = fminf(pg[ch * 2]     - 2.0f * acc[mt][ch * 2][reg],
                                pg[ch * 2 + 1] - 2.0f * acc[mt][ch * 2 + 1][reg]);
#pragma unroll
                for (int m = 8; m >= 1; m >>= 1) v = fminf(v, __shfl_xor(v, m));
                ((float*)&vv)[reg] = v;
            }
            if (mrow == 0) {
                int grow = by * BMs + w * 64 + mt * 16 + quad * 4;
                *(float4*)&min_d[(size_t)cls * B_ + grow] = vv;
            }
        }
    }
}

// ---------- per-sample select: [C][B] layout, class-parallel (proven R5, ~3.5us) ----------
__global__ __launch_bounds__(256)
void select_kernel(const float* __restrict__ min_d, const float* __restrict__ x2,
                   const int* __restrict__ tgt,
                   float* __restrict__ stw, float* __restrict__ sww) {
    const int sb = threadIdx.x & 15;        // sample within block
    const int sl = threadIdx.x >> 4;        // class-slice 0..15
    const int b  = blockIdx.x * 16 + sb;
    const int tc = tgt[b];

    float bw = 3.4e38f, vt = 3.4e38f;
    for (int c = sl; c < C_; c += 16) {
        float v = min_d[(size_t)c * B_ + b];
        if (c == tc) vt = v;
        else         bw = fminf(bw, v);
    }
    bw = fminf(bw, __shfl_xor(bw, 16));
    bw = fminf(bw, __shfl_xor(bw, 32));
    vt = fminf(vt, __shfl_xor(vt, 16));
    vt = fminf(vt, __shfl_xor(vt, 32));

    __shared__ float rbw[4][16], rvt[4][16];
    const int w = threadIdx.x >> 6;
    if ((threadIdx.x & 63) < 16) { rbw[w][sb] = bw; rvt[w][sb] = vt; }
    __syncthreads();
    if (threadIdx.x < 16) {
        float fb = fminf(fminf(rbw[0][sb], rbw[1][sb]), fminf(rbw[2][sb], rbw[3][sb]));
        float fv = fminf(fminf(rvt[0][sb], rvt[1][sb]), fminf(rvt[2][sb], rvt[3][sb]));
        float xx = x2[b];
        stw[b] = xx + fv;        // = ||x - p_target*||^2 (fp8-dot approx)
        sww[b] = xx + fb;        // = ||x - p_wrong*||^2
    }
}

// Single-block reduction of 2x4096 floats + final loss
__global__ __launch_bounds__(1024)
void finalize_kernel(const float* __restrict__ stw, const float* __restrict__ sww,
                     float* __restrict__ out) {
    __shared__ float r1[16], r2[16];
    int tid = threadIdx.x;
    float s1 = 0.f, s2 = 0.f;
#pragma unroll
    for (int i = 0; i < 4; ++i) {
        s1 += stw[tid + i * 1024];
        s2 += sww[tid + i * 1024];
    }
#pragma unroll
    for (int m = 32; m >= 1; m >>= 1) { s1 += __shfl_xor(s1, m); s2 += __shfl_xor(s2, m); }
    if ((tid & 63) == 0) { r1[tid >> 6] = s1; r2[tid >> 6] = s2; }
    __syncthreads();
    if (tid == 0) {
        double t1 = 0.0, t2 = 0.0;
#pragma unroll
        for (int i = 0; i < 16; ++i) { t1 += (double)r1[i]; t2 += (double)r2[i]; }
        double denom = (double)B_ * (double)F_;
        double tl  = t1 / denom;
        double ntl = t2 / denom;
        out[0] = (float)((1.0 - ALPHA_) * tl + ALPHA_ / (ntl + EPS_));
    }
}

// ---------- launch ----------
extern "C" void kernel_launch(void* const* d_in, const int* in_sizes, int n_in,
                              void* d_out, int out_size, void* d_ws, size_t ws_size,
                              hipStream_t stream) {
    const float* outputs  = (const float*)d_in[0];
    const float* clusters = (const float*)d_in[1];
    const int*   tgt      = (const int*)d_in[2];
    float* out = (float*)d_out;

    char* ws = (char*)d_ws;
    // workspace layout (16B-aligned)
    u8*     At      = (u8*)(ws);                     // packed A: 2,097,152
    u8*     Bt      = (u8*)(ws + 2097152);           // packed B: 3,276,800
    float*  sumsq   = (float*)(ws + 5373952);        // 10496*4 (x2 | p2)
    float*  min_d   = (float*)(ws + 5415936);        // [C][B] 200*4096*4
    float*  x2      = sumsq;
    float*  p2      = sumsq + B_;
    // per-sample partials: reuse the At region (dead after score_kernel)
    float*  stw     = (float*)(ws);                  // 4096*4
    float*  sww     = (float*)(ws + 16384);          // 4096*4

    prep_kernel<<<B_ / 16 + N_ / 16, 512, 0, stream>>>(outputs, clusters, At, Bt, sumsq); // 656
    score_kernel<<<(B_ / BMs) * (N_ / BNs), 256, 0, stream>>>(At, Bt, p2, min_d);         // 1600
    select_kernel<<<B_ / 16, 256, 0, stream>>>(min_d, x2, tgt, stw, sww);                 // 256
    finalize_kernel<<<1, 1024, 0, stream>>>(stw, sww, out);
}